// Round 1
// baseline (1557.994 us; speedup 1.0000x reference)
//
#include <hip/hip_runtime.h>
#include <cmath>

#define N_IMG   8
#define PRE     1000
#define K_SEL   5000
#define NBIN    4096
#define TIE_CAP 4096
#define IMG_F   1344.0f
#define S_NEGINF 0x007FFFFFu

__constant__ int c_W[5]   = {336,168,84,42,21};
__constant__ int c_HW[5]  = {112896,28224,7056,1764,441};
__constant__ int c_OFF[5] = {0,338688,423360,444528,449820};

__device__ __forceinline__ unsigned f2s(float f){
  unsigned u = __float_as_uint(f);
  return (u & 0x80000000u) ? ~u : (u | 0x80000000u);
}
__device__ __forceinline__ float s2f(unsigned s){
  unsigned u = (s & 0x80000000u) ? (s & 0x7FFFFFFFu) : ~s;
  return __uint_as_float(u);
}
__device__ __forceinline__ const float* sel5(int l, const float* p0,const float* p1,const float* p2,const float* p3,const float* p4){
  switch(l){case 0:return p0;case 1:return p1;case 2:return p2;case 3:return p3;default:return p4;}
}

struct BoxV { float x1,y1,x2,y2; bool valid; };

// Bit-faithful torchvision BoxCoder.decode + clip + min-size validity.
// Plain rounded ops (no FMA) to match a numpy/XLA elementwise reference;
// exp done in double -> correctly-rounded f32 exp.
__device__ BoxV decode_box(int lvl, int t, int n, const float* dl, const float* anchors){
  int HW = c_HW[lvl], W = c_W[lvl];
  int a = t % 3, pos = t / 3;          // t = (h*W+w)*3 + a
  int h = pos / W, w = pos - h*W;
  int g = c_OFF[lvl] + t;
  const float* an = anchors + (size_t)4*(size_t)g;
  float a0=an[0], a1=an[1], a2=an[2], a3=an[3];
  float aw = __fsub_rn(a2,a0), ah = __fsub_rn(a3,a1);
  float acx = __fadd_rn(a0, __fmul_rn(0.5f,aw));
  float acy = __fadd_rn(a1, __fmul_rn(0.5f,ah));
  const float* dp = dl + ((size_t)n*12 + (size_t)a*4)*(size_t)HW + (size_t)h*W + (size_t)w;
  float dx = dp[0], dy = dp[HW], dwv = dp[2*(size_t)HW], dhv = dp[3*(size_t)HW];
  const float CLAMP = (float)4.135166556742356;  // log(1000/16)
  dwv = fminf(dwv, CLAMP); dhv = fminf(dhv, CLAMP);
  float pcx = __fadd_rn(__fmul_rn(dx,aw), acx);
  float pcy = __fadd_rn(__fmul_rn(dy,ah), acy);
  float pw = __fmul_rn((float)::exp((double)dwv), aw);
  float ph = __fmul_rn((float)::exp((double)dhv), ah);
  float hx = __fmul_rn(0.5f,pw), hy = __fmul_rn(0.5f,ph);
  BoxV b;
  b.x1 = fminf(fmaxf(__fsub_rn(pcx,hx),0.0f),IMG_F);
  b.y1 = fminf(fmaxf(__fsub_rn(pcy,hy),0.0f),IMG_F);
  b.x2 = fminf(fmaxf(__fadd_rn(pcx,hx),0.0f),IMG_F);
  b.y2 = fminf(fmaxf(__fadd_rn(pcy,hy),0.0f),IMG_F);
  b.valid = (__fsub_rn(b.x2,b.x1) >= 1e-3f) && (__fsub_rn(b.y2,b.y1) >= 1e-3f);
  return b;
}

// key = (~s_eff)<<22 | lvl<<19 | t : ascending sort == (score desc, level asc, idx asc)
__device__ unsigned long long make_key(unsigned s, int lvl, int t, int n, const float* dl, const float* anchors){
  BoxV b = decode_box(lvl,t,n,dl,anchors);
  unsigned se = b.valid ? s : S_NEGINF;     // invalid -> skey = -inf
  return ((unsigned long long)(~se) << 22) | ((unsigned long long)(unsigned)lvl << 19) | (unsigned long long)(unsigned)t;
}

// ---------------- K1: per-(image,level) 12-bit score histogram ----------------
__global__ __launch_bounds__(256) void k_hist(const float* o0,const float* o1,const float* o2,const float* o3,const float* o4,
                                              unsigned* hist){
  int grp = blockIdx.y; int n = grp/5, lvl = grp - n*5;
  const float* ob = sel5(lvl,o0,o1,o2,o3,o4);
  int HW = c_HW[lvl], M = 3*HW;
  ob += (size_t)n*(size_t)M;
  __shared__ unsigned lh[NBIN];
  for (int b = threadIdx.x; b < NBIN; b += 256) lh[b] = 0;
  __syncthreads();
  int stride = gridDim.x*256;
  for (int i = blockIdx.x*256 + threadIdx.x; i < M; i += stride){
    unsigned s = f2s(ob[i]);
    atomicAdd(&lh[s >> 20], 1u);
  }
  __syncthreads();
  unsigned* gh = hist + (size_t)grp*NBIN;
  for (int b = threadIdx.x; b < NBIN; b += 256){ unsigned v = lh[b]; if (v) atomicAdd(&gh[b], v); }
}

// ---------------- K2: find bin containing the 1000th-largest score ----------------
__global__ __launch_bounds__(256) void k_scan(const unsigned* hist, unsigned* thi){
  int grp = blockIdx.x;
  const unsigned* gh = hist + (size_t)grp*NBIN;
  __shared__ unsigned part[256];
  unsigned ssum = 0;
  int base = threadIdx.x*16;
  for (int b = base; b < base+16; ++b) ssum += gh[b];
  part[threadIdx.x] = ssum;
  __syncthreads();
  if (threadIdx.x == 0){
    int k = PRE;
    int c = 255;
    while ((int)part[c] < k){ k -= (int)part[c]; --c; }
    int b = c*16 + 15;
    while ((int)gh[b] < k){ k -= (int)gh[b]; --b; }
    thi[grp] = (unsigned)b;
  }
}

// ---------------- K3: compact >bin elements (decode+key), collect ==bin candidates ----------------
__global__ __launch_bounds__(256) void k_compact(const float* o0,const float* o1,const float* o2,const float* o3,const float* o4,
                                                 const float* d0,const float* d1,const float* d2,const float* d3,const float* d4,
                                                 const float* anchors, const unsigned* thi,
                                                 unsigned* cnt_gt, unsigned* cnt_eq,
                                                 unsigned long long* cand, unsigned long long* keys){
  int grp = blockIdx.y; int n = grp/5, lvl = grp - n*5;
  const float* ob = sel5(lvl,o0,o1,o2,o3,o4);
  const float* dl = sel5(lvl,d0,d1,d2,d3,d4);
  int HW = c_HW[lvl], M = 3*HW;
  ob += (size_t)n*(size_t)M;
  unsigned T = thi[grp];
  unsigned long long* kout = keys + (size_t)n*K_SEL + (size_t)lvl*PRE;
  int stride = gridDim.x*256;
  for (int i = blockIdx.x*256 + threadIdx.x; i < M; i += stride){
    unsigned s = f2s(ob[i]);
    unsigned sh = s >> 20;
    if (sh > T){
      unsigned pos = atomicAdd(&cnt_gt[grp], 1u);
      int a = i / HW; int rem = i - a*HW; int t = rem*3 + a;
      kout[pos] = make_key(s, lvl, t, n, dl, anchors);
    } else if (sh == T){
      unsigned e = atomicAdd(&cnt_eq[grp], 1u);
      if (e < TIE_CAP){
        int a = i / HW; int rem = i - a*HW; int t = rem*3 + a;
        cand[(size_t)grp*TIE_CAP + e] = ((unsigned long long)(~s) << 19) | (unsigned long long)(unsigned)t;
      }
    }
  }
}

template<int SZ>
__device__ void bitonic(unsigned long long* sk){
  for (int k = 2; k <= SZ; k <<= 1){
    for (int j = k >> 1; j > 0; j >>= 1){
      for (int i = threadIdx.x; i < SZ; i += blockDim.x){
        int ix = i ^ j;
        if (ix > i){
          unsigned long long va = sk[i], vb = sk[ix];
          if ((va > vb) == ((i & k) == 0)){ sk[i] = vb; sk[ix] = va; }
        }
      }
      __syncthreads();
    }
  }
}

// ---------------- K4: exact boundary selection within the threshold bin ----------------
__global__ __launch_bounds__(256) void k_tiesel(const float* d0,const float* d1,const float* d2,const float* d3,const float* d4,
                                                const float* anchors,
                                                const unsigned* cnt_gt, const unsigned* cnt_eq,
                                                const unsigned long long* cand, unsigned long long* keys){
  int grp = blockIdx.x; int n = grp/5, lvl = grp - n*5;
  __shared__ unsigned long long sk[TIE_CAP];
  int ne = min((int)cnt_eq[grp], TIE_CAP);
  for (int i = threadIdx.x; i < TIE_CAP; i += 256)
    sk[i] = (i < ne) ? cand[(size_t)grp*TIE_CAP + i] : ~0ULL;
  __syncthreads();
  bitonic<TIE_CAP>(sk);              // ascending: (score desc, idx asc)
  int cg = (int)cnt_gt[grp];
  int need = PRE - cg;
  const float* dl = sel5(lvl,d0,d1,d2,d3,d4);
  unsigned long long* kout = keys + (size_t)n*K_SEL + (size_t)lvl*PRE + cg;
  for (int j = threadIdx.x; j < need; j += 256){
    if (j < ne){
      unsigned long long ck = sk[j];
      unsigned t = (unsigned)(ck & 0x7FFFFu);
      unsigned s = ~((unsigned)(ck >> 19));
      kout[j] = make_key(s, lvl, (int)t, n, dl, anchors);
    } else {
      kout[j] = ((unsigned long long)(~S_NEGINF) << 22); // pathological overflow: harmless invalid
    }
  }
}

// ---------------- K5: per-image global sort of 5000 keys + decode to sorted arrays ----------------
__global__ __launch_bounds__(256) void k_sortimg(const unsigned long long* keys,
                                                 const float* d0,const float* d1,const float* d2,const float* d3,const float* d4,
                                                 const float* anchors,
                                                 float4* sbox, float* sskey, int* slvl){
  int n = blockIdx.x;
  __shared__ unsigned long long sk[8192];
  for (int i = threadIdx.x; i < 8192; i += 256)
    sk[i] = (i < K_SEL) ? keys[(size_t)n*K_SEL + i] : ~0ULL;
  __syncthreads();
  bitonic<8192>(sk);
  for (int r = threadIdx.x; r < K_SEL; r += 256){
    unsigned long long key = sk[r];
    int t = (int)(key & 0x7FFFFu);
    int lvl = (int)((key >> 19) & 7u);
    unsigned se = ~((unsigned)(key >> 22));
    const float* dl = sel5(lvl,d0,d1,d2,d3,d4);
    BoxV b = decode_box(lvl, t, n, dl, anchors);
    sbox[(size_t)n*K_SEL + r] = make_float4(b.x1,b.y1,b.x2,b.y2);
    sskey[(size_t)n*K_SEL + r] = s2f(se);   // -inf if invalid
    slvl[(size_t)n*K_SEL + r] = lvl;
  }
}

// ---------------- K6: greedy NMS (offset-coordinate IoU, exact) + output ----------------
__global__ __launch_bounds__(256) void k_nms(const float4* sbox, const float* sskey, const int* slvl, float* out){
  int n = blockIdx.x, tid = threadIdx.x;
  __shared__ float kx1[PRE], ky1[PRE], kx2[PRE], ky2[PRE], kar[PRE];
  __shared__ int klv[PRE];
  __shared__ int nv_s, flag_s;
  for (int i = tid; i < PRE*5; i += 256) out[(size_t)n*PRE*5 + i] = 0.0f;
  if (tid == 0){ nv_s = 0; flag_s = 0; }
  __syncthreads();
  int c = 0;
  for (int i = tid; i < K_SEL; i += 256)
    if (sskey[(size_t)n*K_SEL + i] != -INFINITY) ++c;
  atomicAdd(&nv_s, c);
  __syncthreads();
  int nvalid = nv_s;
  int kept = 0;
  for (int i = 0; i < nvalid; ++i){
    float4 b = sbox[(size_t)n*K_SEL + i];
    int lv = slvl[(size_t)n*K_SEL + i];
    float off = (float)lv * 1345.0f;               // (IMG+1) batched-NMS offset
    float ox1 = __fadd_rn(b.x, off), oy1 = __fadd_rn(b.y, off);
    float ox2 = __fadd_rn(b.z, off), oy2 = __fadd_rn(b.w, off);
    float area = __fmul_rn(__fsub_rn(ox2,ox1), __fsub_rn(oy2,oy1));
    bool hit = false;
    for (int j = tid; j < kept; j += 256){
      if (klv[j] == lv){
        float ltx = fmaxf(kx1[j], ox1), lty = fmaxf(ky1[j], oy1);
        float rbx = fminf(kx2[j], ox2), rby = fminf(ky2[j], oy2);
        float w = fmaxf(__fsub_rn(rbx,ltx), 0.0f);
        float h = fmaxf(__fsub_rn(rby,lty), 0.0f);
        float inter = __fmul_rn(w,h);
        float uni = __fsub_rn(__fadd_rn(kar[j], area), inter);
        if (__fdiv_rn(inter,uni) > 0.7f) hit = true;
      }
    }
    if (hit) flag_s = 1;
    __syncthreads();                 // (a) all hit-writes visible
    int sup = flag_s;
    __syncthreads();                 // (b) all reads done before reset/append
    if (!sup){
      if (tid == 0){
        kx1[kept]=ox1; ky1[kept]=oy1; kx2[kept]=ox2; ky2[kept]=oy2; kar[kept]=area; klv[kept]=lv;
        float* orow = out + (size_t)n*PRE*5 + (size_t)kept*5;
        orow[0]=b.x; orow[1]=b.y; orow[2]=b.z; orow[3]=b.w;
        orow[4]=sskey[(size_t)n*K_SEL + i];
      }
      ++kept;
    }
    if (tid == 0) flag_s = 0;
    __syncthreads();                 // (c) append + reset visible
    if (kept == PRE) break;
  }
}

extern "C" void kernel_launch(void* const* d_in, const int* in_sizes, int n_in,
                              void* d_out, int out_size, void* d_ws, size_t ws_size,
                              hipStream_t stream) {
  // setup_inputs inserts obj_i and delta_i interleaved; detect defensively.
  bool interleaved = (in_sizes[1] == 4*in_sizes[0]);
  const float* obj[5]; const float* dlt[5];
  for (int i = 0; i < 5; ++i){
    if (interleaved){ obj[i] = (const float*)d_in[2*i]; dlt[i] = (const float*)d_in[2*i+1]; }
    else            { obj[i] = (const float*)d_in[i];   dlt[i] = (const float*)d_in[5+i]; }
  }
  const float* anchors = (const float*)d_in[10];

  char* ws = (char*)d_ws;
  unsigned* hist            = (unsigned*)(ws);                 // 40*4096*4 = 655360
  unsigned* cnt_gt          = (unsigned*)(ws + 655360);        // 160
  unsigned* cnt_eq          = (unsigned*)(ws + 655520);        // 160
  unsigned* thi             = (unsigned*)(ws + 655680);        // 160
  unsigned long long* cand  = (unsigned long long*)(ws + 655840);   // 40*4096*8 = 1310720
  unsigned long long* keys  = (unsigned long long*)(ws + 1966560);  // 8*5000*8 = 320000
  float4* sbox              = (float4*)(ws + 2286560);         // 8*5000*16 = 640000
  float* sskey              = (float*)(ws + 2926560);          // 160000
  int* slvl                 = (int*)(ws + 3086560);            // 160000 (end 3246560)

  hipMemsetAsync(ws, 0, 655840, stream);   // hist + counters

  dim3 gScan(8, 40);
  k_hist<<<gScan, 256, 0, stream>>>(obj[0],obj[1],obj[2],obj[3],obj[4], hist);
  k_scan<<<40, 256, 0, stream>>>(hist, thi);
  k_compact<<<gScan, 256, 0, stream>>>(obj[0],obj[1],obj[2],obj[3],obj[4],
                                       dlt[0],dlt[1],dlt[2],dlt[3],dlt[4],
                                       anchors, thi, cnt_gt, cnt_eq, cand, keys);
  k_tiesel<<<40, 256, 0, stream>>>(dlt[0],dlt[1],dlt[2],dlt[3],dlt[4], anchors,
                                   cnt_gt, cnt_eq, cand, keys);
  k_sortimg<<<8, 256, 0, stream>>>(keys, dlt[0],dlt[1],dlt[2],dlt[3],dlt[4], anchors,
                                   sbox, sskey, slvl);
  k_nms<<<8, 256, 0, stream>>>(sbox, sskey, slvl, (float*)d_out);
}

// Round 3
// 1100.365 us; speedup vs baseline: 1.4159x; 1.4159x over previous
//
#include <hip/hip_runtime.h>
#include <cmath>

#define N_IMG   8
#define PRE     1000
#define K_SEL   5000
#define NBIN    4096
#define TIE_CAP 4096
#define IMG_F   1344.0f
#define S_NEGINF 0x007FFFFFu
#define MAT_W   160            // u32 words per bit-matrix row (5120 bits >= 5000)
#define JCHUNK  2048
#define ROWS_PB 160

__constant__ int c_W[5]   = {336,168,84,42,21};
__constant__ int c_HW[5]  = {112896,28224,7056,1764,441};
__constant__ int c_OFF[5] = {0,338688,423360,444528,449820};

__device__ __forceinline__ unsigned f2s(float f){
  unsigned u = __float_as_uint(f);
  return (u & 0x80000000u) ? ~u : (u | 0x80000000u);
}
__device__ __forceinline__ float s2f(unsigned s){
  unsigned u = (s & 0x80000000u) ? (s & 0x7FFFFFFFu) : ~s;
  return __uint_as_float(u);
}
__device__ __forceinline__ const float* sel5(int l, const float* p0,const float* p1,const float* p2,const float* p3,const float* p4){
  switch(l){case 0:return p0;case 1:return p1;case 2:return p2;case 3:return p3;default:return p4;}
}

struct BoxV { float x1,y1,x2,y2; bool valid; };

// Bit-faithful torchvision BoxCoder.decode + clip + min-size validity.
__device__ BoxV decode_box(int lvl, int t, int n, const float* dl, const float* anchors){
  int HW = c_HW[lvl], W = c_W[lvl];
  int a = t % 3, pos = t / 3;          // t = (h*W+w)*3 + a
  int h = pos / W, w = pos - h*W;
  int g = c_OFF[lvl] + t;
  const float* an = anchors + (size_t)4*(size_t)g;
  float a0=an[0], a1=an[1], a2=an[2], a3=an[3];
  float aw = __fsub_rn(a2,a0), ah = __fsub_rn(a3,a1);
  float acx = __fadd_rn(a0, __fmul_rn(0.5f,aw));
  float acy = __fadd_rn(a1, __fmul_rn(0.5f,ah));
  const float* dp = dl + ((size_t)n*12 + (size_t)a*4)*(size_t)HW + (size_t)h*W + (size_t)w;
  float dx = dp[0], dy = dp[HW], dwv = dp[2*(size_t)HW], dhv = dp[3*(size_t)HW];
  const float CLAMP = (float)4.135166556742356;  // log(1000/16)
  dwv = fminf(dwv, CLAMP); dhv = fminf(dhv, CLAMP);
  float pcx = __fadd_rn(__fmul_rn(dx,aw), acx);
  float pcy = __fadd_rn(__fmul_rn(dy,ah), acy);
  float pw = __fmul_rn((float)::exp((double)dwv), aw);
  float ph = __fmul_rn((float)::exp((double)dhv), ah);
  float hx = __fmul_rn(0.5f,pw), hy = __fmul_rn(0.5f,ph);
  BoxV b;
  b.x1 = fminf(fmaxf(__fsub_rn(pcx,hx),0.0f),IMG_F);
  b.y1 = fminf(fmaxf(__fsub_rn(pcy,hy),0.0f),IMG_F);
  b.x2 = fminf(fmaxf(__fadd_rn(pcx,hx),0.0f),IMG_F);
  b.y2 = fminf(fmaxf(__fadd_rn(pcy,hy),0.0f),IMG_F);
  b.valid = (__fsub_rn(b.x2,b.x1) >= 1e-3f) && (__fsub_rn(b.y2,b.y1) >= 1e-3f);
  return b;
}

// key = (~s_eff)<<22 | lvl<<19 | t : ascending sort == (score desc, level asc, idx asc)
__device__ unsigned long long make_key(unsigned s, int lvl, int t, int n, const float* dl, const float* anchors){
  BoxV b = decode_box(lvl,t,n,dl,anchors);
  unsigned se = b.valid ? s : S_NEGINF;     // invalid -> skey = -inf
  return ((unsigned long long)(~se) << 22) | ((unsigned long long)(unsigned)lvl << 19) | (unsigned long long)(unsigned)t;
}

// ---------------- K1: per-(image,level) 12-bit score histogram ----------------
__global__ __launch_bounds__(256) void k_hist(const float* o0,const float* o1,const float* o2,const float* o3,const float* o4,
                                              unsigned* hist){
  int grp = blockIdx.y; int n = grp/5, lvl = grp - n*5;
  const float* ob = sel5(lvl,o0,o1,o2,o3,o4);
  int HW = c_HW[lvl], M = 3*HW;
  ob += (size_t)n*(size_t)M;
  __shared__ unsigned lh[NBIN];
  for (int b = threadIdx.x; b < NBIN; b += 256) lh[b] = 0;
  __syncthreads();
  int stride = gridDim.x*256;
  for (int i = blockIdx.x*256 + threadIdx.x; i < M; i += stride){
    unsigned s = f2s(ob[i]);
    atomicAdd(&lh[s >> 20], 1u);
  }
  __syncthreads();
  unsigned* gh = hist + (size_t)grp*NBIN;
  for (int b = threadIdx.x; b < NBIN; b += 256){ unsigned v = lh[b]; if (v) atomicAdd(&gh[b], v); }
}

// ---------------- K2: find bin containing the 1000th-largest score ----------------
__global__ __launch_bounds__(256) void k_scan(const unsigned* hist, unsigned* thi){
  int grp = blockIdx.x;
  const unsigned* gh = hist + (size_t)grp*NBIN;
  __shared__ unsigned part[256];
  unsigned ssum = 0;
  int base = threadIdx.x*16;
  for (int b = base; b < base+16; ++b) ssum += gh[b];
  part[threadIdx.x] = ssum;
  __syncthreads();
  if (threadIdx.x == 0){
    int k = PRE;
    int c = 255;
    while ((int)part[c] < k){ k -= (int)part[c]; --c; }
    int b = c*16 + 15;
    while ((int)gh[b] < k){ k -= (int)gh[b]; --b; }
    thi[grp] = (unsigned)b;
  }
}

// ---------------- K3: compact >bin elements (decode+key), collect ==bin candidates ----------------
__global__ __launch_bounds__(256) void k_compact(const float* o0,const float* o1,const float* o2,const float* o3,const float* o4,
                                                 const float* d0,const float* d1,const float* d2,const float* d3,const float* d4,
                                                 const float* anchors, const unsigned* thi,
                                                 unsigned* cnt_gt, unsigned* cnt_eq,
                                                 unsigned long long* cand, unsigned long long* keys){
  int grp = blockIdx.y; int n = grp/5, lvl = grp - n*5;
  const float* ob = sel5(lvl,o0,o1,o2,o3,o4);
  const float* dl = sel5(lvl,d0,d1,d2,d3,d4);
  int HW = c_HW[lvl], M = 3*HW;
  ob += (size_t)n*(size_t)M;
  unsigned T = thi[grp];
  unsigned long long* kout = keys + (size_t)n*K_SEL + (size_t)lvl*PRE;
  int stride = gridDim.x*256;
  for (int i = blockIdx.x*256 + threadIdx.x; i < M; i += stride){
    unsigned s = f2s(ob[i]);
    unsigned sh = s >> 20;
    if (sh > T){
      unsigned pos = atomicAdd(&cnt_gt[grp], 1u);
      int a = i / HW; int rem = i - a*HW; int t = rem*3 + a;
      kout[pos] = make_key(s, lvl, t, n, dl, anchors);
    } else if (sh == T){
      unsigned e = atomicAdd(&cnt_eq[grp], 1u);
      if (e < TIE_CAP){
        int a = i / HW; int rem = i - a*HW; int t = rem*3 + a;
        cand[(size_t)grp*TIE_CAP + e] = ((unsigned long long)(~s) << 19) | (unsigned long long)(unsigned)t;
      }
    }
  }
}

template<int SZ>
__device__ void bitonic(unsigned long long* sk){
  for (int k = 2; k <= SZ; k <<= 1){
    for (int j = k >> 1; j > 0; j >>= 1){
      for (int i = threadIdx.x; i < SZ; i += blockDim.x){
        int ix = i ^ j;
        if (ix > i){
          unsigned long long va = sk[i], vb = sk[ix];
          if ((va > vb) == ((i & k) == 0)){ sk[i] = vb; sk[ix] = va; }
        }
      }
      __syncthreads();
    }
  }
}

// ---------------- K4: exact boundary selection within the threshold bin ----------------
__global__ __launch_bounds__(256) void k_tiesel(const float* d0,const float* d1,const float* d2,const float* d3,const float* d4,
                                                const float* anchors,
                                                const unsigned* cnt_gt, const unsigned* cnt_eq,
                                                const unsigned long long* cand, unsigned long long* keys){
  int grp = blockIdx.x; int n = grp/5, lvl = grp - n*5;
  __shared__ unsigned long long sk[TIE_CAP];
  int ne = min((int)cnt_eq[grp], TIE_CAP);
  for (int i = threadIdx.x; i < TIE_CAP; i += 256)
    sk[i] = (i < ne) ? cand[(size_t)grp*TIE_CAP + i] : ~0ULL;
  __syncthreads();
  bitonic<TIE_CAP>(sk);              // ascending: (score desc, idx asc)
  int cg = (int)cnt_gt[grp];
  int need = PRE - cg;
  const float* dl = sel5(lvl,d0,d1,d2,d3,d4);
  unsigned long long* kout = keys + (size_t)n*K_SEL + (size_t)lvl*PRE + cg;
  for (int j = threadIdx.x; j < need; j += 256){
    if (j < ne){
      unsigned long long ck = sk[j];
      unsigned t = (unsigned)(ck & 0x7FFFFu);
      unsigned s = ~((unsigned)(ck >> 19));
      kout[j] = make_key(s, lvl, (int)t, n, dl, anchors);
    } else {
      kout[j] = ((unsigned long long)(~S_NEGINF) << 22); // pathological overflow: harmless invalid
    }
  }
}

// ---------------- K5: per-image global sort of 5000 keys + decode to sorted arrays ----------------
__global__ __launch_bounds__(256) void k_sortimg(const unsigned long long* keys,
                                                 const float* d0,const float* d1,const float* d2,const float* d3,const float* d4,
                                                 const float* anchors,
                                                 float4* sbox, float* sskey, int* slvl,
                                                 float4* obox, float* oarea, unsigned* vmask){
  int n = blockIdx.x;
  __shared__ unsigned long long sk[8192];
  for (int i = threadIdx.x; i < 8192; i += 256)
    sk[i] = (i < K_SEL) ? keys[(size_t)n*K_SEL + i] : ~0ULL;
  __syncthreads();
  bitonic<8192>(sk);
  for (int r = threadIdx.x; r < K_SEL; r += 256){
    unsigned long long key = sk[r];
    int t = (int)(key & 0x7FFFFu);
    int lvl = (int)((key >> 19) & 7u);
    unsigned se = ~((unsigned)(key >> 22));
    const float* dl = sel5(lvl,d0,d1,d2,d3,d4);
    BoxV b = decode_box(lvl, t, n, dl, anchors);
    sbox[(size_t)n*K_SEL + r] = make_float4(b.x1,b.y1,b.x2,b.y2);
    sskey[(size_t)n*K_SEL + r] = s2f(se);   // -inf if invalid
    slvl[(size_t)n*K_SEL + r] = lvl;
    // offset coords + area for the IoU matrix (exactly as the reference's batched-NMS)
    float off = (float)lvl * 1345.0f;
    float ox1 = __fadd_rn(b.x1, off), oy1 = __fadd_rn(b.y1, off);
    float ox2 = __fadd_rn(b.x2, off), oy2 = __fadd_rn(b.y2, off);
    obox[(size_t)n*K_SEL + r] = make_float4(ox1,oy1,ox2,oy2);
    oarea[(size_t)n*K_SEL + r] = __fmul_rn(__fsub_rn(ox2,ox1), __fsub_rn(oy2,oy1));
  }
  __syncthreads();
  // validity bitmask: 160 u32 words (5120 bits, pad bits 0)
  for (int r = threadIdx.x; r < MAT_W*32; r += 256){
    bool val = false;
    if (r < K_SEL){
      unsigned se = ~((unsigned)(sk[r] >> 22));
      val = (se != S_NEGINF);
    }
    unsigned long long bal = __ballot(val);
    int lane = threadIdx.x & 63;
    int rbase = r - lane;
    int word0 = rbase >> 5;
    if (lane == 0)       vmask[(size_t)n*MAT_W + word0]     = (unsigned)bal;
    else if (lane == 32) vmask[(size_t)n*MAT_W + word0 + 1] = (unsigned)(bal >> 32);
  }
}

// ---------------- K6a: suppression bit-matrix (j>i, offset-coordinate IoU) ----------------
__global__ __launch_bounds__(256) void k_ioumat(const float4* obox, const float* oarea, unsigned* mat){
  int n = blockIdx.y;
  int ic = blockIdx.x / 3, jc = blockIdx.x % 3;
  __shared__ float sx1[JCHUNK], sy1[JCHUNK], sx2[JCHUNK], sy2[JCHUNK], sar[JCHUNK];
  int jbase = jc*JCHUNK;
  for (int t = threadIdx.x; t < JCHUNK; t += 256){
    int j = jbase + t;
    float4 bb = make_float4(0.f,0.f,0.f,0.f); float ar = 0.f;
    if (j < K_SEL){ bb = obox[(size_t)n*K_SEL + j]; ar = oarea[(size_t)n*K_SEL + j]; }
    sx1[t]=bb.x; sy1[t]=bb.y; sx2[t]=bb.z; sy2[t]=bb.w; sar[t]=ar;
  }
  __syncthreads();
  int lane = threadIdx.x & 63;
  int i0 = ic*ROWS_PB;
  unsigned* matn = mat + (size_t)n*K_SEL*MAT_W;
  for (int t = threadIdx.x; t < ROWS_PB*64; t += 256){
    int rl = t >> 6, w = t & 63;       // w == lane within the wave
    int i = i0 + rl;
    if (i >= K_SEL) break;
    int widx = jc*64 + w;              // word index within the 160-word row
    if (widx >= MAT_W) continue;       // FIX: jc=2,w>=32 would overflow into row i+1
    unsigned* wout = matn + (size_t)i*MAT_W + widx;
    if (i >= jbase + JCHUNK){ *wout = 0u; continue; }   // whole chunk is j<=i
    float4 bi = obox[(size_t)n*K_SEL + i];  // uniform per wave
    float ai = oarea[(size_t)n*K_SEL + i];
    unsigned bits = 0u;
    int cbase = w << 5;
    #pragma unroll
    for (int jj = 0; jj < 32; ++jj){
      int js = (jj + lane) & 31;        // lane-rotated -> 2-way LDS aliasing (free)
      int jl = cbase + js;
      int jg = jbase + jl;
      float ltx = fmaxf(bi.x, sx1[jl]), lty = fmaxf(bi.y, sy1[jl]);
      float rbx = fminf(bi.z, sx2[jl]), rby = fminf(bi.w, sy2[jl]);
      float ww = fmaxf(__fsub_rn(rbx,ltx), 0.0f);
      float hh = fmaxf(__fsub_rn(rby,lty), 0.0f);
      float inter = __fmul_rn(ww,hh);
      float uni = __fsub_rn(__fadd_rn(ai, sar[jl]), inter);
      bool hit = (__fdiv_rn(inter,uni) > 0.7f) && (jg > i) && (jg < K_SEL);
      bits |= (hit ? 1u : 0u) << js;
    }
    *wout = bits;
  }
}

// ---------------- K6b: serial greedy scan, one wave per image, zero barriers ----------------
#define DPF 16
__global__ __launch_bounds__(64) void k_scan_nms(const unsigned* mat, const unsigned* vmask,
                                                 const float4* sbox, const float* sskey, float* out){
  int n = blockIdx.x; int lane = threadIdx.x;
  const unsigned* matn = mat + (size_t)n*K_SEL*MAT_W;
  const unsigned* vm = vmask + (size_t)n*MAT_W;
  unsigned v0 = vm[lane], v1 = vm[lane+64], v2 = (lane<32) ? vm[lane+128] : 0u;
  unsigned s0=0u, s1=0u, s2=0u;
  unsigned a0[DPF],a1[DPF],a2[DPF], b0[DPF],b1[DPF],b2[DPF];
#define LDROW(A0,A1,A2,d,row_) { int r_ = (row_); r_ = r_ < K_SEL ? r_ : K_SEL-1; \
    const unsigned* rp_ = matn + (size_t)r_*MAT_W; \
    A0[d] = rp_[lane]; A1[d] = rp_[lane+64]; A2[d] = (lane<32) ? rp_[lane+128] : 0u; }
  #pragma unroll
  for (int d=0; d<DPF; ++d) LDROW(a0,a1,a2,d, d);
  #pragma unroll
  for (int d=0; d<DPF; ++d) LDROW(b0,b1,b2,d, DPF+d);
  int kept = 0;
  float* outn = out + (size_t)n*PRE*5;
  for (int base = 0; base < K_SEL; base += 2*DPF){
    #pragma unroll
    for (int d=0; d<DPF; ++d){
      int i = base + d;
      if (i < K_SEL){
        int w = i >> 5; unsigned sel = ((unsigned)w) >> 6;
        unsigned myk = (sel==0u) ? (v0 & ~s0) : (sel==1u) ? (v1 & ~s1) : (v2 & ~s2);
        unsigned kw = __shfl(myk, w & 63);
        if ((kw >> (i & 31)) & 1u){
          s0 |= a0[d]; s1 |= a1[d]; s2 |= a2[d];
          if (kept < PRE && lane == 0){
            float4 bb = sbox[(size_t)n*K_SEL + i];
            float sc = sskey[(size_t)n*K_SEL + i];
            float* orow = outn + (size_t)kept*5;
            orow[0]=bb.x; orow[1]=bb.y; orow[2]=bb.z; orow[3]=bb.w; orow[4]=sc;
          }
          ++kept;
        }
      }
    }
    #pragma unroll
    for (int d=0; d<DPF; ++d) LDROW(a0,a1,a2,d, base + 2*DPF + d);
    #pragma unroll
    for (int d=0; d<DPF; ++d){
      int i = base + DPF + d;
      if (i < K_SEL){
        int w = i >> 5; unsigned sel = ((unsigned)w) >> 6;
        unsigned myk = (sel==0u) ? (v0 & ~s0) : (sel==1u) ? (v1 & ~s1) : (v2 & ~s2);
        unsigned kw = __shfl(myk, w & 63);
        if ((kw >> (i & 31)) & 1u){
          s0 |= b0[d]; s1 |= b1[d]; s2 |= b2[d];
          if (kept < PRE && lane == 0){
            float4 bb = sbox[(size_t)n*K_SEL + i];
            float sc = sskey[(size_t)n*K_SEL + i];
            float* orow = outn + (size_t)kept*5;
            orow[0]=bb.x; orow[1]=bb.y; orow[2]=bb.z; orow[3]=bb.w; orow[4]=sc;
          }
          ++kept;
        }
      }
    }
    #pragma unroll
    for (int d=0; d<DPF; ++d) LDROW(b0,b1,b2,d, base + 3*DPF + d);
    if (kept >= PRE) break;
  }
#undef LDROW
}

// ---------------- fallback (old serial NMS) used only if ws is too small ----------------
__global__ __launch_bounds__(256) void k_nms(const float4* sbox, const float* sskey, const int* slvl, float* out){
  int n = blockIdx.x, tid = threadIdx.x;
  __shared__ float kx1[PRE], ky1[PRE], kx2[PRE], ky2[PRE], kar[PRE];
  __shared__ int klv[PRE];
  __shared__ int nv_s, flag_s;
  for (int i = tid; i < PRE*5; i += 256) out[(size_t)n*PRE*5 + i] = 0.0f;
  if (tid == 0){ nv_s = 0; flag_s = 0; }
  __syncthreads();
  int c = 0;
  for (int i = tid; i < K_SEL; i += 256)
    if (sskey[(size_t)n*K_SEL + i] != -INFINITY) ++c;
  atomicAdd(&nv_s, c);
  __syncthreads();
  int nvalid = nv_s;
  int kept = 0;
  for (int i = 0; i < nvalid; ++i){
    float4 b = sbox[(size_t)n*K_SEL + i];
    int lv = slvl[(size_t)n*K_SEL + i];
    float off = (float)lv * 1345.0f;
    float ox1 = __fadd_rn(b.x, off), oy1 = __fadd_rn(b.y, off);
    float ox2 = __fadd_rn(b.z, off), oy2 = __fadd_rn(b.w, off);
    float area = __fmul_rn(__fsub_rn(ox2,ox1), __fsub_rn(oy2,oy1));
    bool hit = false;
    for (int j = tid; j < kept; j += 256){
      if (klv[j] == lv){
        float ltx = fmaxf(kx1[j], ox1), lty = fmaxf(ky1[j], oy1);
        float rbx = fminf(kx2[j], ox2), rby = fminf(ky2[j], oy2);
        float w = fmaxf(__fsub_rn(rbx,ltx), 0.0f);
        float h = fmaxf(__fsub_rn(rby,lty), 0.0f);
        float inter = __fmul_rn(w,h);
        float uni = __fsub_rn(__fadd_rn(kar[j], area), inter);
        if (__fdiv_rn(inter,uni) > 0.7f) hit = true;
      }
    }
    if (hit) flag_s = 1;
    __syncthreads();
    int sup = flag_s;
    __syncthreads();
    if (!sup){
      if (tid == 0){
        kx1[kept]=ox1; ky1[kept]=oy1; kx2[kept]=ox2; ky2[kept]=oy2; kar[kept]=area; klv[kept]=lv;
        float* orow = out + (size_t)n*PRE*5 + (size_t)kept*5;
        orow[0]=b.x; orow[1]=b.y; orow[2]=b.z; orow[3]=b.w;
        orow[4]=sskey[(size_t)n*K_SEL + i];
      }
      ++kept;
    }
    if (tid == 0) flag_s = 0;
    __syncthreads();
    if (kept == PRE) break;
  }
}

extern "C" void kernel_launch(void* const* d_in, const int* in_sizes, int n_in,
                              void* d_out, int out_size, void* d_ws, size_t ws_size,
                              hipStream_t stream) {
  bool interleaved = (in_sizes[1] == 4*in_sizes[0]);
  const float* obj[5]; const float* dlt[5];
  for (int i = 0; i < 5; ++i){
    if (interleaved){ obj[i] = (const float*)d_in[2*i]; dlt[i] = (const float*)d_in[2*i+1]; }
    else            { obj[i] = (const float*)d_in[i];   dlt[i] = (const float*)d_in[5+i]; }
  }
  const float* anchors = (const float*)d_in[10];

  char* ws = (char*)d_ws;
  unsigned* hist            = (unsigned*)(ws);                     // 655360
  unsigned* cnt_gt          = (unsigned*)(ws + 655360);            // 160
  unsigned* cnt_eq          = (unsigned*)(ws + 655520);            // 160
  unsigned* thi             = (unsigned*)(ws + 655680);            // 160
  unsigned long long* cand  = (unsigned long long*)(ws + 655840);  // 1310720
  unsigned long long* keys  = (unsigned long long*)(ws + 1966560); // 320000
  float4* sbox              = (float4*)(ws + 2286560);             // 640000
  float* sskey              = (float*)(ws + 2926560);              // 160000
  int* slvl                 = (int*)(ws + 3086560);                // 160000
  float4* obox              = (float4*)(ws + 3246560);             // 640000
  float* oarea              = (float*)(ws + 3886560);              // 160000
  unsigned* vmask           = (unsigned*)(ws + 4046560);           // 5120
  unsigned* mat             = (unsigned*)(ws + 4051712);           // 25600000 (end 29651712)
  const size_t NEED = 29651712;

  hipMemsetAsync(ws, 0, 655840, stream);   // hist + counters

  dim3 gScan(8, 40);
  k_hist<<<gScan, 256, 0, stream>>>(obj[0],obj[1],obj[2],obj[3],obj[4], hist);
  k_scan<<<40, 256, 0, stream>>>(hist, thi);
  k_compact<<<gScan, 256, 0, stream>>>(obj[0],obj[1],obj[2],obj[3],obj[4],
                                       dlt[0],dlt[1],dlt[2],dlt[3],dlt[4],
                                       anchors, thi, cnt_gt, cnt_eq, cand, keys);
  k_tiesel<<<40, 256, 0, stream>>>(dlt[0],dlt[1],dlt[2],dlt[3],dlt[4], anchors,
                                   cnt_gt, cnt_eq, cand, keys);
  k_sortimg<<<8, 256, 0, stream>>>(keys, dlt[0],dlt[1],dlt[2],dlt[3],dlt[4], anchors,
                                   sbox, sskey, slvl, obox, oarea, vmask);
  if (ws_size >= NEED){
    hipMemsetAsync(d_out, 0, (size_t)out_size*sizeof(float), stream);
    k_ioumat<<<dim3(96, 8), 256, 0, stream>>>(obox, oarea, mat);
    k_scan_nms<<<8, 64, 0, stream>>>(mat, vmask, sbox, sskey, (float*)d_out);
  } else {
    k_nms<<<8, 256, 0, stream>>>(sbox, sskey, slvl, (float*)d_out);
  }
}

// Round 4
// 764.358 us; speedup vs baseline: 2.0383x; 1.4396x over previous
//
#include <hip/hip_runtime.h>
#include <cmath>

#define N_IMG   8
#define PRE     1000
#define K_SEL   5000
#define NBIN    4096
#define TIE_CAP 4096
#define IMG_F   1344.0f
#define S_NEGINF 0x007FFFFFu
#define MAT_W   160            // u32 words per bit-matrix row (5120 bits >= 5000)
#define JCHUNK  2048
#define ROWS_PB 160

__constant__ int c_W[5]   = {336,168,84,42,21};
__constant__ int c_HW[5]  = {112896,28224,7056,1764,441};
__constant__ int c_OFF[5] = {0,338688,423360,444528,449820};

__device__ __forceinline__ unsigned f2s(float f){
  unsigned u = __float_as_uint(f);
  return (u & 0x80000000u) ? ~u : (u | 0x80000000u);
}
__device__ __forceinline__ float s2f(unsigned s){
  unsigned u = (s & 0x80000000u) ? (s & 0x7FFFFFFFu) : ~s;
  return __uint_as_float(u);
}
__device__ __forceinline__ const float* sel5(int l, const float* p0,const float* p1,const float* p2,const float* p3,const float* p4){
  switch(l){case 0:return p0;case 1:return p1;case 2:return p2;case 3:return p3;default:return p4;}
}

struct BoxV { float x1,y1,x2,y2; bool valid; };

// Bit-faithful torchvision BoxCoder.decode + clip + min-size validity.
__device__ BoxV decode_box(int lvl, int t, int n, const float* dl, const float* anchors){
  int HW = c_HW[lvl], W = c_W[lvl];
  int a = t % 3, pos = t / 3;          // t = (h*W+w)*3 + a
  int h = pos / W, w = pos - h*W;
  int g = c_OFF[lvl] + t;
  const float* an = anchors + (size_t)4*(size_t)g;
  float a0=an[0], a1=an[1], a2=an[2], a3=an[3];
  float aw = __fsub_rn(a2,a0), ah = __fsub_rn(a3,a1);
  float acx = __fadd_rn(a0, __fmul_rn(0.5f,aw));
  float acy = __fadd_rn(a1, __fmul_rn(0.5f,ah));
  const float* dp = dl + ((size_t)n*12 + (size_t)a*4)*(size_t)HW + (size_t)h*W + (size_t)w;
  float dx = dp[0], dy = dp[HW], dwv = dp[2*(size_t)HW], dhv = dp[3*(size_t)HW];
  const float CLAMP = (float)4.135166556742356;  // log(1000/16)
  dwv = fminf(dwv, CLAMP); dhv = fminf(dhv, CLAMP);
  float pcx = __fadd_rn(__fmul_rn(dx,aw), acx);
  float pcy = __fadd_rn(__fmul_rn(dy,ah), acy);
  float pw = __fmul_rn((float)::exp((double)dwv), aw);
  float ph = __fmul_rn((float)::exp((double)dhv), ah);
  float hx = __fmul_rn(0.5f,pw), hy = __fmul_rn(0.5f,ph);
  BoxV b;
  b.x1 = fminf(fmaxf(__fsub_rn(pcx,hx),0.0f),IMG_F);
  b.y1 = fminf(fmaxf(__fsub_rn(pcy,hy),0.0f),IMG_F);
  b.x2 = fminf(fmaxf(__fadd_rn(pcx,hx),0.0f),IMG_F);
  b.y2 = fminf(fmaxf(__fadd_rn(pcy,hy),0.0f),IMG_F);
  b.valid = (__fsub_rn(b.x2,b.x1) >= 1e-3f) && (__fsub_rn(b.y2,b.y1) >= 1e-3f);
  return b;
}

// key = (~s_eff)<<22 | lvl<<19 | t : ascending sort == (score desc, level asc, idx asc)
__device__ unsigned long long make_key(unsigned s, int lvl, int t, int n, const float* dl, const float* anchors){
  BoxV b = decode_box(lvl,t,n,dl,anchors);
  unsigned se = b.valid ? s : S_NEGINF;     // invalid -> skey = -inf
  return ((unsigned long long)(~se) << 22) | ((unsigned long long)(unsigned)lvl << 19) | (unsigned long long)(unsigned)t;
}

// ---------------- K1: per-(image,level) 12-bit score histogram ----------------
__global__ __launch_bounds__(256) void k_hist(const float* o0,const float* o1,const float* o2,const float* o3,const float* o4,
                                              unsigned* hist){
  int grp = blockIdx.y; int n = grp/5, lvl = grp - n*5;
  const float* ob = sel5(lvl,o0,o1,o2,o3,o4);
  int HW = c_HW[lvl], M = 3*HW;
  ob += (size_t)n*(size_t)M;
  __shared__ unsigned lh[NBIN];
  for (int b = threadIdx.x; b < NBIN; b += 256) lh[b] = 0;
  __syncthreads();
  int stride = gridDim.x*256;
  for (int i = blockIdx.x*256 + threadIdx.x; i < M; i += stride){
    unsigned s = f2s(ob[i]);
    atomicAdd(&lh[s >> 20], 1u);
  }
  __syncthreads();
  unsigned* gh = hist + (size_t)grp*NBIN;
  for (int b = threadIdx.x; b < NBIN; b += 256){ unsigned v = lh[b]; if (v) atomicAdd(&gh[b], v); }
}

// ---------------- K2: find bin containing the 1000th-largest score ----------------
__global__ __launch_bounds__(256) void k_scan(const unsigned* hist, unsigned* thi){
  int grp = blockIdx.x;
  const unsigned* gh = hist + (size_t)grp*NBIN;
  __shared__ unsigned part[256];
  unsigned ssum = 0;
  int base = threadIdx.x*16;
  for (int b = base; b < base+16; ++b) ssum += gh[b];
  part[threadIdx.x] = ssum;
  __syncthreads();
  if (threadIdx.x == 0){
    int k = PRE;
    int c = 255;
    while ((int)part[c] < k){ k -= (int)part[c]; --c; }
    int b = c*16 + 15;
    while ((int)gh[b] < k){ k -= (int)gh[b]; --b; }
    thi[grp] = (unsigned)b;
  }
}

// ---------------- K3: compact >bin elements (decode+key), collect ==bin candidates ----------------
__global__ __launch_bounds__(256) void k_compact(const float* o0,const float* o1,const float* o2,const float* o3,const float* o4,
                                                 const float* d0,const float* d1,const float* d2,const float* d3,const float* d4,
                                                 const float* anchors, const unsigned* thi,
                                                 unsigned* cnt_gt, unsigned* cnt_eq,
                                                 unsigned long long* cand, unsigned long long* keys){
  int grp = blockIdx.y; int n = grp/5, lvl = grp - n*5;
  const float* ob = sel5(lvl,o0,o1,o2,o3,o4);
  const float* dl = sel5(lvl,d0,d1,d2,d3,d4);
  int HW = c_HW[lvl], M = 3*HW;
  ob += (size_t)n*(size_t)M;
  unsigned T = thi[grp];
  unsigned long long* kout = keys + (size_t)n*K_SEL + (size_t)lvl*PRE;
  int stride = gridDim.x*256;
  for (int i = blockIdx.x*256 + threadIdx.x; i < M; i += stride){
    unsigned s = f2s(ob[i]);
    unsigned sh = s >> 20;
    if (sh > T){
      unsigned pos = atomicAdd(&cnt_gt[grp], 1u);
      int a = i / HW; int rem = i - a*HW; int t = rem*3 + a;
      kout[pos] = make_key(s, lvl, t, n, dl, anchors);
    } else if (sh == T){
      unsigned e = atomicAdd(&cnt_eq[grp], 1u);
      if (e < TIE_CAP){
        int a = i / HW; int rem = i - a*HW; int t = rem*3 + a;
        cand[(size_t)grp*TIE_CAP + e] = ((unsigned long long)(~s) << 19) | (unsigned long long)(unsigned)t;
      }
    }
  }
}

template<int SZ>
__device__ void bitonic(unsigned long long* sk){
  for (int k = 2; k <= SZ; k <<= 1){
    for (int j = k >> 1; j > 0; j >>= 1){
      for (int i = threadIdx.x; i < SZ; i += blockDim.x){
        int ix = i ^ j;
        if (ix > i){
          unsigned long long va = sk[i], vb = sk[ix];
          if ((va > vb) == ((i & k) == 0)){ sk[i] = vb; sk[ix] = va; }
        }
      }
      __syncthreads();
    }
  }
}

// runtime-sized bitonic (SZ uniform across block, power of 2)
__device__ void bitonic_rt(unsigned long long* sk, int SZ){
  for (int k = 2; k <= SZ; k <<= 1){
    for (int j = k >> 1; j > 0; j >>= 1){
      for (int i = threadIdx.x; i < SZ; i += blockDim.x){
        int ix = i ^ j;
        if (ix > i){
          unsigned long long va = sk[i], vb = sk[ix];
          if ((va > vb) == ((i & k) == 0)){ sk[i] = vb; sk[ix] = va; }
        }
      }
      __syncthreads();
    }
  }
}

// ---------------- K4: exact boundary selection within the threshold bin ----------------
__global__ __launch_bounds__(256) void k_tiesel(const float* d0,const float* d1,const float* d2,const float* d3,const float* d4,
                                                const float* anchors,
                                                const unsigned* cnt_gt, const unsigned* cnt_eq,
                                                const unsigned long long* cand, unsigned long long* keys){
  int grp = blockIdx.x; int n = grp/5, lvl = grp - n*5;
  __shared__ unsigned long long sk[TIE_CAP];
  int ne = min((int)cnt_eq[grp], TIE_CAP);
  int SZ = 64; while (SZ < ne) SZ <<= 1;    // runtime pow2 >= ne (uniform)
  for (int i = threadIdx.x; i < SZ; i += 256)
    sk[i] = (i < ne) ? cand[(size_t)grp*TIE_CAP + i] : ~0ULL;
  __syncthreads();
  bitonic_rt(sk, SZ);                // ascending: (score desc, idx asc)
  int cg = (int)cnt_gt[grp];
  int need = PRE - cg;
  const float* dl = sel5(lvl,d0,d1,d2,d3,d4);
  unsigned long long* kout = keys + (size_t)n*K_SEL + (size_t)lvl*PRE + cg;
  for (int j = threadIdx.x; j < need; j += 256){
    if (j < ne){
      unsigned long long ck = sk[j];
      unsigned t = (unsigned)(ck & 0x7FFFFu);
      unsigned s = ~((unsigned)(ck >> 19));
      kout[j] = make_key(s, lvl, (int)t, n, dl, anchors);
    } else {
      kout[j] = ((unsigned long long)(~S_NEGINF) << 22); // pathological overflow: harmless invalid
    }
  }
}

// ---------------- K5a: sort each (image,level) run of 1000 keys ----------------
__global__ __launch_bounds__(256) void k_sortlvl(unsigned long long* keys){
  int grp = blockIdx.x; int n = grp/5, lvl = grp - n*5;
  __shared__ unsigned long long sk[1024];
  unsigned long long* kp = keys + (size_t)n*K_SEL + (size_t)lvl*PRE;
  for (int i = threadIdx.x; i < 1024; i += 256)
    sk[i] = (i < PRE) ? kp[i] : ~0ULL;
  __syncthreads();
  bitonic<1024>(sk);
  for (int i = threadIdx.x; i < PRE; i += 256) kp[i] = sk[i];
}

// ---------------- K5b: merge 5 sorted runs by rank (keys globally unique) ----------------
__global__ __launch_bounds__(256) void k_rank(const unsigned long long* keys, unsigned long long* ranked){
  int grp = blockIdx.x; int n = grp/5, lvl = grp - n*5;
  __shared__ unsigned long long sl[K_SEL];
  for (int i = threadIdx.x; i < K_SEL; i += 256) sl[i] = keys[(size_t)n*K_SEL + i];
  __syncthreads();
  for (int j = threadIdx.x; j < PRE; j += 256){
    unsigned long long k = sl[lvl*PRE + j];
    int rank = j;
    #pragma unroll
    for (int m = 0; m < 5; ++m){
      if (m == lvl) continue;
      const unsigned long long* s = sl + m*PRE;
      int lo = 0, hi = PRE;
      while (lo < hi){ int mid = (lo+hi) >> 1; if (s[mid] < k) lo = mid+1; else hi = mid; }
      rank += lo;
    }
    ranked[(size_t)n*K_SEL + rank] = k;   // exact permutation: same order as global sort
  }
}

// ---------------- K5c: decode rank-ordered keys -> sorted arrays + validity bits ----------------
__global__ __launch_bounds__(256) void k_decode(const unsigned long long* ranked,
                                                const float* d0,const float* d1,const float* d2,const float* d3,const float* d4,
                                                const float* anchors,
                                                float4* sbox, float* sskey, int* slvl,
                                                float4* obox, float* oarea, unsigned* vmask){
  int n = blockIdx.y, chunk = blockIdx.x;   // grid (5, 8), chunk = 1024 positions (word-aligned)
  int base = chunk*1024;
  for (int rr = threadIdx.x; rr < 1024; rr += 256){
    int r = base + rr;
    bool val = false;
    if (r < K_SEL){
      unsigned long long key = ranked[(size_t)n*K_SEL + r];
      int t = (int)(key & 0x7FFFFu);
      int lvl = (int)((key >> 19) & 7u);
      unsigned se = ~((unsigned)(key >> 22));
      const float* dl = sel5(lvl,d0,d1,d2,d3,d4);
      BoxV b = decode_box(lvl, t, n, dl, anchors);
      sbox[(size_t)n*K_SEL + r] = make_float4(b.x1,b.y1,b.x2,b.y2);
      sskey[(size_t)n*K_SEL + r] = s2f(se);   // -inf if invalid
      slvl[(size_t)n*K_SEL + r] = lvl;
      float off = (float)lvl * 1345.0f;
      float ox1 = __fadd_rn(b.x1, off), oy1 = __fadd_rn(b.y1, off);
      float ox2 = __fadd_rn(b.x2, off), oy2 = __fadd_rn(b.y2, off);
      obox[(size_t)n*K_SEL + r] = make_float4(ox1,oy1,ox2,oy2);
      oarea[(size_t)n*K_SEL + r] = __fmul_rn(__fsub_rn(ox2,ox1), __fsub_rn(oy2,oy1));
      val = (se != S_NEGINF);
    }
    unsigned long long bal = __ballot(val);
    int lane = threadIdx.x & 63;
    int word0 = (r - lane) >> 5;
    if (lane == 0)       vmask[(size_t)n*MAT_W + word0]     = (unsigned)bal;
    else if (lane == 32) vmask[(size_t)n*MAT_W + word0 + 1] = (unsigned)(bal >> 32);
  }
}

// ---------------- K5 (fallback): per-image global sort of 5000 keys + decode ----------------
__global__ __launch_bounds__(256) void k_sortimg(const unsigned long long* keys,
                                                 const float* d0,const float* d1,const float* d2,const float* d3,const float* d4,
                                                 const float* anchors,
                                                 float4* sbox, float* sskey, int* slvl,
                                                 float4* obox, float* oarea, unsigned* vmask){
  int n = blockIdx.x;
  __shared__ unsigned long long sk[8192];
  for (int i = threadIdx.x; i < 8192; i += 256)
    sk[i] = (i < K_SEL) ? keys[(size_t)n*K_SEL + i] : ~0ULL;
  __syncthreads();
  bitonic<8192>(sk);
  for (int r = threadIdx.x; r < K_SEL; r += 256){
    unsigned long long key = sk[r];
    int t = (int)(key & 0x7FFFFu);
    int lvl = (int)((key >> 19) & 7u);
    unsigned se = ~((unsigned)(key >> 22));
    const float* dl = sel5(lvl,d0,d1,d2,d3,d4);
    BoxV b = decode_box(lvl, t, n, dl, anchors);
    sbox[(size_t)n*K_SEL + r] = make_float4(b.x1,b.y1,b.x2,b.y2);
    sskey[(size_t)n*K_SEL + r] = s2f(se);
    slvl[(size_t)n*K_SEL + r] = lvl;
    float off = (float)lvl * 1345.0f;
    float ox1 = __fadd_rn(b.x1, off), oy1 = __fadd_rn(b.y1, off);
    float ox2 = __fadd_rn(b.x2, off), oy2 = __fadd_rn(b.y2, off);
    obox[(size_t)n*K_SEL + r] = make_float4(ox1,oy1,ox2,oy2);
    oarea[(size_t)n*K_SEL + r] = __fmul_rn(__fsub_rn(ox2,ox1), __fsub_rn(oy2,oy1));
  }
  __syncthreads();
  for (int r = threadIdx.x; r < MAT_W*32; r += 256){
    bool val = false;
    if (r < K_SEL){
      unsigned se = ~((unsigned)(sk[r] >> 22));
      val = (se != S_NEGINF);
    }
    unsigned long long bal = __ballot(val);
    int lane = threadIdx.x & 63;
    int rbase = r - lane;
    int word0 = rbase >> 5;
    if (lane == 0)       vmask[(size_t)n*MAT_W + word0]     = (unsigned)bal;
    else if (lane == 32) vmask[(size_t)n*MAT_W + word0 + 1] = (unsigned)(bal >> 32);
  }
}

// ---------------- K6a: suppression bit-matrix (j>i, offset-coordinate IoU) ----------------
__global__ __launch_bounds__(256) void k_ioumat(const float4* obox, const float* oarea, unsigned* mat){
  int n = blockIdx.y;
  int ic = blockIdx.x / 3, jc = blockIdx.x % 3;
  __shared__ float sx1[JCHUNK], sy1[JCHUNK], sx2[JCHUNK], sy2[JCHUNK], sar[JCHUNK];
  int jbase = jc*JCHUNK;
  for (int t = threadIdx.x; t < JCHUNK; t += 256){
    int j = jbase + t;
    float4 bb = make_float4(0.f,0.f,0.f,0.f); float ar = 0.f;
    if (j < K_SEL){ bb = obox[(size_t)n*K_SEL + j]; ar = oarea[(size_t)n*K_SEL + j]; }
    sx1[t]=bb.x; sy1[t]=bb.y; sx2[t]=bb.z; sy2[t]=bb.w; sar[t]=ar;
  }
  __syncthreads();
  int lane = threadIdx.x & 63;
  int i0 = ic*ROWS_PB;
  unsigned* matn = mat + (size_t)n*K_SEL*MAT_W;
  for (int t = threadIdx.x; t < ROWS_PB*64; t += 256){
    int rl = t >> 6, w = t & 63;       // w == lane within the wave
    int i = i0 + rl;
    if (i >= K_SEL) break;
    int widx = jc*64 + w;              // word index within the 160-word row
    if (widx >= MAT_W) continue;
    unsigned* wout = matn + (size_t)i*MAT_W + widx;
    if (i >= jbase + JCHUNK){ *wout = 0u; continue; }   // whole chunk is j<=i
    float4 bi = obox[(size_t)n*K_SEL + i];  // uniform per wave
    float ai = oarea[(size_t)n*K_SEL + i];
    unsigned bits = 0u;
    int cbase = w << 5;
    #pragma unroll
    for (int jj = 0; jj < 32; ++jj){
      int js = (jj + lane) & 31;        // lane-rotated -> 2-way LDS aliasing (free)
      int jl = cbase + js;
      int jg = jbase + jl;
      float ltx = fmaxf(bi.x, sx1[jl]), lty = fmaxf(bi.y, sy1[jl]);
      float rbx = fminf(bi.z, sx2[jl]), rby = fminf(bi.w, sy2[jl]);
      float ww = fmaxf(__fsub_rn(rbx,ltx), 0.0f);
      float hh = fmaxf(__fsub_rn(rby,lty), 0.0f);
      float inter = __fmul_rn(ww,hh);
      float uni = __fsub_rn(__fadd_rn(ai, sar[jl]), inter);
      bool hit = (__fdiv_rn(inter,uni) > 0.7f) && (jg > i) && (jg < K_SEL);
      bits |= (hit ? 1u : 0u) << js;
    }
    *wout = bits;
  }
}

// ---------------- K6b: serial greedy scan, one wave per image, zero barriers ----------------
#define DPF 16
__global__ __launch_bounds__(64) void k_scan_nms(const unsigned* mat, const unsigned* vmask,
                                                 const float4* sbox, const float* sskey, float* out){
  int n = blockIdx.x; int lane = threadIdx.x;
  const unsigned* matn = mat + (size_t)n*K_SEL*MAT_W;
  const unsigned* vm = vmask + (size_t)n*MAT_W;
  unsigned v0 = vm[lane], v1 = vm[lane+64], v2 = (lane<32) ? vm[lane+128] : 0u;
  unsigned s0=0u, s1=0u, s2=0u;
  unsigned a0[DPF],a1[DPF],a2[DPF], b0[DPF],b1[DPF],b2[DPF];
#define LDROW(A0,A1,A2,d,row_) { int r_ = (row_); r_ = r_ < K_SEL ? r_ : K_SEL-1; \
    const unsigned* rp_ = matn + (size_t)r_*MAT_W; \
    A0[d] = rp_[lane]; A1[d] = rp_[lane+64]; A2[d] = (lane<32) ? rp_[lane+128] : 0u; }
  #pragma unroll
  for (int d=0; d<DPF; ++d) LDROW(a0,a1,a2,d, d);
  #pragma unroll
  for (int d=0; d<DPF; ++d) LDROW(b0,b1,b2,d, DPF+d);
  int kept = 0;
  float* outn = out + (size_t)n*PRE*5;
  for (int base = 0; base < K_SEL; base += 2*DPF){
    #pragma unroll
    for (int d=0; d<DPF; ++d){
      int i = base + d;
      if (i < K_SEL){
        int w = i >> 5; unsigned sel = ((unsigned)w) >> 6;
        unsigned myk = (sel==0u) ? (v0 & ~s0) : (sel==1u) ? (v1 & ~s1) : (v2 & ~s2);
        unsigned kw = __shfl(myk, w & 63);
        if ((kw >> (i & 31)) & 1u){
          s0 |= a0[d]; s1 |= a1[d]; s2 |= a2[d];
          if (kept < PRE && lane == 0){
            float4 bb = sbox[(size_t)n*K_SEL + i];
            float sc = sskey[(size_t)n*K_SEL + i];
            float* orow = outn + (size_t)kept*5;
            orow[0]=bb.x; orow[1]=bb.y; orow[2]=bb.z; orow[3]=bb.w; orow[4]=sc;
          }
          ++kept;
        }
      }
    }
    #pragma unroll
    for (int d=0; d<DPF; ++d) LDROW(a0,a1,a2,d, base + 2*DPF + d);
    #pragma unroll
    for (int d=0; d<DPF; ++d){
      int i = base + DPF + d;
      if (i < K_SEL){
        int w = i >> 5; unsigned sel = ((unsigned)w) >> 6;
        unsigned myk = (sel==0u) ? (v0 & ~s0) : (sel==1u) ? (v1 & ~s1) : (v2 & ~s2);
        unsigned kw = __shfl(myk, w & 63);
        if ((kw >> (i & 31)) & 1u){
          s0 |= b0[d]; s1 |= b1[d]; s2 |= b2[d];
          if (kept < PRE && lane == 0){
            float4 bb = sbox[(size_t)n*K_SEL + i];
            float sc = sskey[(size_t)n*K_SEL + i];
            float* orow = outn + (size_t)kept*5;
            orow[0]=bb.x; orow[1]=bb.y; orow[2]=bb.z; orow[3]=bb.w; orow[4]=sc;
          }
          ++kept;
        }
      }
    }
    #pragma unroll
    for (int d=0; d<DPF; ++d) LDROW(b0,b1,b2,d, base + 3*DPF + d);
    if (kept >= PRE) break;
  }
#undef LDROW
}

// ---------------- fallback (old serial NMS) used only if ws is too small ----------------
__global__ __launch_bounds__(256) void k_nms(const float4* sbox, const float* sskey, const int* slvl, float* out){
  int n = blockIdx.x, tid = threadIdx.x;
  __shared__ float kx1[PRE], ky1[PRE], kx2[PRE], ky2[PRE], kar[PRE];
  __shared__ int klv[PRE];
  __shared__ int nv_s, flag_s;
  for (int i = tid; i < PRE*5; i += 256) out[(size_t)n*PRE*5 + i] = 0.0f;
  if (tid == 0){ nv_s = 0; flag_s = 0; }
  __syncthreads();
  int c = 0;
  for (int i = tid; i < K_SEL; i += 256)
    if (sskey[(size_t)n*K_SEL + i] != -INFINITY) ++c;
  atomicAdd(&nv_s, c);
  __syncthreads();
  int nvalid = nv_s;
  int kept = 0;
  for (int i = 0; i < nvalid; ++i){
    float4 b = sbox[(size_t)n*K_SEL + i];
    int lv = slvl[(size_t)n*K_SEL + i];
    float off = (float)lv * 1345.0f;
    float ox1 = __fadd_rn(b.x, off), oy1 = __fadd_rn(b.y, off);
    float ox2 = __fadd_rn(b.z, off), oy2 = __fadd_rn(b.w, off);
    float area = __fmul_rn(__fsub_rn(ox2,ox1), __fsub_rn(oy2,oy1));
    bool hit = false;
    for (int j = tid; j < kept; j += 256){
      if (klv[j] == lv){
        float ltx = fmaxf(kx1[j], ox1), lty = fmaxf(ky1[j], oy1);
        float rbx = fminf(kx2[j], ox2), rby = fminf(ky2[j], oy2);
        float w = fmaxf(__fsub_rn(rbx,ltx), 0.0f);
        float h = fmaxf(__fsub_rn(rby,lty), 0.0f);
        float inter = __fmul_rn(w,h);
        float uni = __fsub_rn(__fadd_rn(kar[j], area), inter);
        if (__fdiv_rn(inter,uni) > 0.7f) hit = true;
      }
    }
    if (hit) flag_s = 1;
    __syncthreads();
    int sup = flag_s;
    __syncthreads();
    if (!sup){
      if (tid == 0){
        kx1[kept]=ox1; ky1[kept]=oy1; kx2[kept]=ox2; ky2[kept]=oy2; kar[kept]=area; klv[kept]=lv;
        float* orow = out + (size_t)n*PRE*5 + (size_t)kept*5;
        orow[0]=b.x; orow[1]=b.y; orow[2]=b.z; orow[3]=b.w;
        orow[4]=sskey[(size_t)n*K_SEL + i];
      }
      ++kept;
    }
    if (tid == 0) flag_s = 0;
    __syncthreads();
    if (kept == PRE) break;
  }
}

extern "C" void kernel_launch(void* const* d_in, const int* in_sizes, int n_in,
                              void* d_out, int out_size, void* d_ws, size_t ws_size,
                              hipStream_t stream) {
  bool interleaved = (in_sizes[1] == 4*in_sizes[0]);
  const float* obj[5]; const float* dlt[5];
  for (int i = 0; i < 5; ++i){
    if (interleaved){ obj[i] = (const float*)d_in[2*i]; dlt[i] = (const float*)d_in[2*i+1]; }
    else            { obj[i] = (const float*)d_in[i];   dlt[i] = (const float*)d_in[5+i]; }
  }
  const float* anchors = (const float*)d_in[10];

  char* ws = (char*)d_ws;
  unsigned* hist            = (unsigned*)(ws);                     // 655360
  unsigned* cnt_gt          = (unsigned*)(ws + 655360);            // 160
  unsigned* cnt_eq          = (unsigned*)(ws + 655520);            // 160
  unsigned* thi             = (unsigned*)(ws + 655680);            // 160
  unsigned long long* cand  = (unsigned long long*)(ws + 655840);  // 1310720
  unsigned long long* ranked= (unsigned long long*)(ws + 655840);  // aliases cand (done after k_tiesel)
  unsigned long long* keys  = (unsigned long long*)(ws + 1966560); // 320000
  float4* sbox              = (float4*)(ws + 2286560);             // 640000
  float* sskey              = (float*)(ws + 2926560);              // 160000
  int* slvl                 = (int*)(ws + 3086560);                // 160000
  float4* obox              = (float4*)(ws + 3246560);             // 640000
  float* oarea              = (float*)(ws + 3886560);              // 160000
  unsigned* vmask           = (unsigned*)(ws + 4046560);           // 5120
  unsigned* mat             = (unsigned*)(ws + 4051712);           // 25600000 (end 29651712)
  const size_t NEED = 29651712;

  hipMemsetAsync(ws, 0, 655840, stream);   // hist + counters

  dim3 gScan(8, 40);
  k_hist<<<gScan, 256, 0, stream>>>(obj[0],obj[1],obj[2],obj[3],obj[4], hist);
  k_scan<<<40, 256, 0, stream>>>(hist, thi);
  k_compact<<<gScan, 256, 0, stream>>>(obj[0],obj[1],obj[2],obj[3],obj[4],
                                       dlt[0],dlt[1],dlt[2],dlt[3],dlt[4],
                                       anchors, thi, cnt_gt, cnt_eq, cand, keys);
  k_tiesel<<<40, 256, 0, stream>>>(dlt[0],dlt[1],dlt[2],dlt[3],dlt[4], anchors,
                                   cnt_gt, cnt_eq, cand, keys);
  if (ws_size >= NEED){
    k_sortlvl<<<40, 256, 0, stream>>>(keys);
    k_rank<<<40, 256, 0, stream>>>(keys, ranked);
    k_decode<<<dim3(5, 8), 256, 0, stream>>>(ranked, dlt[0],dlt[1],dlt[2],dlt[3],dlt[4], anchors,
                                             sbox, sskey, slvl, obox, oarea, vmask);
    hipMemsetAsync(d_out, 0, (size_t)out_size*sizeof(float), stream);
    k_ioumat<<<dim3(96, 8), 256, 0, stream>>>(obox, oarea, mat);
    k_scan_nms<<<8, 64, 0, stream>>>(mat, vmask, sbox, sskey, (float*)d_out);
  } else {
    k_sortimg<<<8, 256, 0, stream>>>(keys, dlt[0],dlt[1],dlt[2],dlt[3],dlt[4], anchors,
                                     sbox, sskey, slvl, obox, oarea, vmask);
    k_nms<<<8, 256, 0, stream>>>(sbox, sskey, slvl, (float*)d_out);
  }
}